// Round 12
// baseline (348.598 us; speedup 1.0000x reference)
//
#include <hip/hip_runtime.h>

#define TT 4096          // signal length
#define NN 8192          // padded length
#define NF 4096          // FFT length = 16^3

// XOR swizzle (generic form, used only in the fwd epilogue where the index
// does not decompose cleanly).  For i = 256A + 16B + j (A,B,j < 16):
//   SW(i) = 256A + 16B + (j ^ A ^ B)   -- used in closed form in the stages.
#define SW(i) ((i) ^ ((((i) >> 4) ^ ((i) >> 8)) & 15))

// packed pair of floats: signal-0 component in .x, signal-1 in .y.
// All dual-signal arithmetic on pf is lane-pure -> LLVM selects
// v_pk_{add,mul,fma}_f32 (VOP3P), halving VALU issue.
typedef __attribute__((ext_vector_type(2))) float pf;

// hardware sin/cos of 2*pi*x (x in revolutions); args here are exact dyadics
__device__ __forceinline__ float sin2pi(float x) { return __builtin_amdgcn_sinf(x); }
__device__ __forceinline__ float cos2pi(float x) { return __builtin_amdgcn_cosf(x); }

// (ar,ai) *= (br,bi) -- scalar complex mul (twiddle recurrences)
#define WMUL(ar, ai, br, bi) { float _t = (ar)*(br) - (ai)*(bi); \
                               (ai) = (ar)*(bi) + (ai)*(br); (ar) = _t; }

// e^{i*2*pi/32} — step for k -> k+256 at N=8192
#define C32 0.9807852804032304f
#define S32 0.19509032201612825f

// Output-slot permutation of the no-permute DFT16: natural output q lives in
// register slot PQ[q] = 4*(q&3) + (q>>2) (an involution).
__device__ __constant__ const int PQ[16] =
    {0, 4, 8, 12, 1, 5, 9, 13, 2, 6, 10, 14, 3, 7, 11, 15};

// -------------------- register DFT16 (two radix-4 layers, DIT) --------------
// S = -1: forward (e^{-i}), S = +1: inverse (e^{+i}).  T = float or pf.
template<int S, typename T>
__device__ __forceinline__ void dft4(T& ar, T& ai, T& br, T& bi,
                                     T& cr, T& ci, T& er, T& ei) {
    T t0r = ar + cr, t0i = ai + ci;
    T t1r = ar - cr, t1i = ai - ci;
    T t2r = br + er, t2i = bi + ei;
    T t3r = br - er, t3i = bi - ei;
    ar = t0r + t2r; ai = t0i + t2i;
    cr = t0r - t2r; ci = t0i - t2i;
    br = t1r - (float)S * t3i; bi = t1i + (float)S * t3r;
    er = t1r + (float)S * t3i; ei = t1i - (float)S * t3r;
}

template<int S, typename T>
__device__ __forceinline__ void tmuls16(T xr[16], T xi[16]) {
    const float C1 = 0.9238795325112867f;   // cos(pi/8)
    const float S1 = 0.3826834323650898f;   // sin(pi/8)
    const float R2 = 0.7071067811865476f;
    #define TM(idx, wr, wi) { T _r = xr[idx]*(wr) - xi[idx]*(wi); \
                              xi[idx] = xr[idx]*(wi) + xi[idx]*(wr); xr[idx] = _r; }
    TM(5,  C1,  (float)S * S1)
    TM(9,  R2,  (float)S * R2)
    TM(13, S1,  (float)S * C1)
    TM(6,  R2,  (float)S * R2)
    { T _r = -(float)S * xi[10]; xi[10] = (float)S * xr[10]; xr[10] = _r; }
    TM(14, -R2, (float)S * R2)
    TM(7,  S1,  (float)S * C1)
    TM(11, -R2, (float)S * R2)
    TM(15, -C1, -(float)S * S1)
    #undef TM
}

// No-permute DFT16: natural output q is left in slot PQ[q].
template<int S, typename T>
__device__ __forceinline__ void dft16_np(T xr[16], T xi[16]) {
    #pragma unroll
    for (int n0 = 0; n0 < 4; ++n0)
        dft4<S>(xr[n0], xi[n0], xr[n0 + 4], xi[n0 + 4],
                xr[n0 + 8], xi[n0 + 8], xr[n0 + 12], xi[n0 + 12]);

    tmuls16<S>(xr, xi);

    #pragma unroll
    for (int k0 = 0; k0 < 4; ++k0)
        dft4<S>(xr[4*k0], xi[4*k0], xr[4*k0+1], xi[4*k0+1],
                xr[4*k0+2], xi[4*k0+2], xr[4*k0+3], xi[4*k0+3]);
}

// Post-DFT twiddle on no-permute layout: applies w^q to slot PQ[q].
// Scalar recurrence; exact reset to w^8 at the midpoint caps the chain.
template<typename T>
__device__ __forceinline__ void twiddle16_p(T xr[16], T xi[16],
                                            float w1r, float w1i,
                                            float w8r, float w8i) {
    float wr = w1r, wi = w1i;
    #pragma unroll
    for (int q = 1; q < 16; ++q) {
        const int p = PQ[q];
        T _r = xr[p]*wr - xi[p]*wi;
        xi[p] = xr[p]*wi + xi[p]*wr; xr[p] = _r;
        if (q == 7) { wr = w8r; wi = w8i; }
        else        { WMUL(wr, wi, w1r, w1i) }
    }
}

// Pruned final-stage DFT16 (natural inputs): only natural outputs q in [4,12)
// are needed.  y[i2] corresponds to natural output q = 4+i2.
template<int S, typename T>
__device__ __forceinline__ void dft16_mid8(T xr[16], T xi[16],
                                           T yr[8], T yi[8]) {
    #pragma unroll
    for (int n0 = 0; n0 < 4; ++n0)
        dft4<S>(xr[n0], xi[n0], xr[n0 + 4], xi[n0 + 4],
                xr[n0 + 8], xi[n0 + 8], xr[n0 + 12], xi[n0 + 12]);

    tmuls16<S>(xr, xi);

    #pragma unroll
    for (int k0 = 0; k0 < 4; ++k0) {
        T ar = xr[4*k0],     ai = xi[4*k0];
        T br = xr[4*k0 + 1], bi = xi[4*k0 + 1];
        T cr = xr[4*k0 + 2], ci = xi[4*k0 + 2];
        T er = xr[4*k0 + 3], ei = xi[4*k0 + 3];
        T t0r = ar + cr, t0i = ai + ci;
        T t1r = ar - cr, t1i = ai - ci;
        T t2r = br + er, t2i = bi + ei;
        T t3r = br - er, t3i = bi - ei;
        yr[k0]     = t1r - (float)S * t3i;  yi[k0]     = t1i + (float)S * t3r;  // q = 4+k0
        yr[4 + k0] = t0r - t2r;             yi[4 + k0] = t0i - t2i;             // q = 8+k0
    }
}

__device__ __forceinline__ int refl(int p) {
    if (p < 2048) return 2047 - p;
    if (p < 6144) return p - 2048;
    return 10239 - p;
}

// -------------------- fwd task: real-8192 FFT via packed complex-4096 --------
// Verbatim R11 fwd math; 32 KB float2 view of the block's LDS.
__device__ void fwd_body(const float* __restrict__ in, float2* __restrict__ F,
                         float2* lds, int b, int tid) {
    const int jj = tid & 15, h = tid >> 4, cx = jj ^ h;
    const float* row = in + b * TT;

    float xr[16], xi[16];

    #pragma unroll
    for (int r = 0; r < 16; ++r) {
        const int i = tid + 256 * r;
        xr[r] = row[refl(2 * i)];
        xi[r] = row[refl(2 * i + 1)];
    }
    dft16_np<-1>(xr, xi);
    twiddle16_p(xr, xi,
                cos2pi((float)tid * (1.0f / 4096.0f)), -sin2pi((float)tid * (1.0f / 4096.0f)),
                cos2pi((float)tid * (1.0f / 512.0f)),  -sin2pi((float)tid * (1.0f / 512.0f)));
    #pragma unroll
    for (int q = 0; q < 16; ++q)
        lds[(q << 8) + (h << 4) + (cx ^ q)] = make_float2(xr[PQ[q]], xi[PQ[q]]);
    __syncthreads();

    {
        #pragma unroll
        for (int q = 0; q < 16; ++q) {
            float2 v = lds[(h << 8) + (q << 4) + (cx ^ q)];
            xr[q] = v.x; xi[q] = v.y;
        }
        dft16_np<-1>(xr, xi);
        twiddle16_p(xr, xi,
                    cos2pi((float)jj * (1.0f / 256.0f)), -sin2pi((float)jj * (1.0f / 256.0f)),
                    cos2pi((float)jj * (1.0f / 32.0f)),  -sin2pi((float)jj * (1.0f / 32.0f)));
        #pragma unroll
        for (int q = 0; q < 16; ++q)
            lds[(h << 8) + (q << 4) + (cx ^ q)] = make_float2(xr[PQ[q]], xi[PQ[q]]);
    }
    __syncthreads();

    {
        #pragma unroll
        for (int q = 0; q < 16; ++q) {
            float2 v = lds[(h << 8) + (jj << 4) + (cx ^ q)];
            xr[q] = v.x; xi[q] = v.y;
        }
        dft16_np<-1>(xr, xi);
        __syncthreads();
        #pragma unroll
        for (int q = 0; q < 16; ++q)
            lds[(q << 8) + (jj << 4) + (cx ^ q)] = make_float2(xr[PQ[q]], xi[PQ[q]]);
    }
    __syncthreads();

    {
        const float c0 = cos2pi((float)(tid + 1) * (1.0f / 8192.0f));
        const float s0 = sin2pi((float)(tid + 1) * (1.0f / 8192.0f));
        float cc = c0, ss = s0;
        #pragma unroll
        for (int r = 0; r < 16; ++r) {
            const int i = tid + 256 * r;
            const int k = i + 1;
            const float2 za = lds[SW(k & (NF - 1))];
            const float2 zb = lds[SW((NF - k) & (NF - 1))];
            const float fer = 0.5f * (za.x + zb.x), fei = 0.5f * (za.y - zb.y);
            const float fo_r = 0.5f * (za.y + zb.y), fo_i = -0.5f * (za.x - zb.x);
            F[b * NF + i] = make_float2(fer + cc * fo_r + ss * fo_i,
                                        fei + cc * fo_i - ss * fo_r);
            if (r == 7) { cc = -s0; ss = c0; }        // exact: * e^{i*pi/2}
            else        { WMUL(cc, ss, C32, S32) }
        }
    }
}

// -------------------- inv task: one (batch, scale) pair ----------------------
// Verbatim R11 inv math: packed-pair (pf) dual-signal body, component-split
// transposes through the 32 KB pf buffer (re/im planes independent during
// pure data movement; reads land in slots the writes freed).
__device__ void inv_body(const float2* __restrict__ F, const float* __restrict__ wft,
                         float* __restrict__ out, pf* lds,
                         int b, int j, int tid, int NS) {
    const int jj = tid & 15, h = tid >> 4, cx = jj ^ h;
    const float2* Frow = F + b * NF;
    const float* wrow = wft + (size_t)j * NN + 1;
    float* orow = out + (size_t)(b * NS + j) * TT;
    const float LOGN = 9.0109131020007136f;       // log(8192)
    const float HALF_LN2 = 0.34657359027997264f;  // 0.5 * ln(2)

    pf xr[16], xi[16];

    // ---- staging + stage 0 (stride 256), fused in registers ----
    {
        const float c0 = cos2pi((float)tid * (1.0f / 8192.0f));
        const float s0 = sin2pi((float)tid * (1.0f / 8192.0f));
        float cr = c0, ci = s0;
        #pragma unroll
        for (int r = 0; r < 16; ++r) {
            const int k = tid + 256 * r;
            const float2 f = Frow[k];
            const float w = wrow[k];
            const float d0r = f.x * w, d0i = f.y * w;
            pf vr, vi;
            vr.x = d0r;  vr.y = d0r * cr - d0i * ci;
            vi.x = d0i;  vi.y = d0r * ci + d0i * cr;
            xr[r] = vr;  xi[r] = vi;
            if (r == 7) { cr = -s0; ci = c0; }
            else        { WMUL(cr, ci, C32, S32) }
        }
    }
    dft16_np<1>(xr, xi);
    twiddle16_p(xr, xi,
                cos2pi((float)tid * (1.0f / 4096.0f)), sin2pi((float)tid * (1.0f / 4096.0f)),
                cos2pi((float)tid * (1.0f / 512.0f)),  sin2pi((float)tid * (1.0f / 512.0f)));

    // ---- transpose T1 (stage0 -> stage1), component-split through 32 KB ----
    #pragma unroll
    for (int q = 0; q < 16; ++q)
        lds[(q << 8) + (h << 4) + (cx ^ q)] = xr[PQ[q]];
    __syncthreads();
    #pragma unroll
    for (int q = 0; q < 16; ++q)
        xr[q] = lds[(h << 8) + (q << 4) + (cx ^ q)];
    __syncthreads();
    #pragma unroll
    for (int q = 0; q < 16; ++q)
        lds[(q << 8) + (h << 4) + (cx ^ q)] = xi[PQ[q]];
    __syncthreads();
    #pragma unroll
    for (int q = 0; q < 16; ++q)
        xi[q] = lds[(h << 8) + (q << 4) + (cx ^ q)];
    __syncthreads();

    // ---- stage 1 (stride 16) ----
    dft16_np<1>(xr, xi);
    twiddle16_p(xr, xi,
                cos2pi((float)jj * (1.0f / 256.0f)), sin2pi((float)jj * (1.0f / 256.0f)),
                cos2pi((float)jj * (1.0f / 32.0f)),  sin2pi((float)jj * (1.0f / 32.0f)));

    // ---- transpose T2 (stage1 -> stage2), component-split ----
    #pragma unroll
    for (int q = 0; q < 16; ++q)
        lds[(h << 8) + (q << 4) + (cx ^ q)] = xr[PQ[q]];
    __syncthreads();
    #pragma unroll
    for (int q = 0; q < 16; ++q)
        xr[q] = lds[(jj << 8) + (h << 4) + (cx ^ q)];
    __syncthreads();
    #pragma unroll
    for (int q = 0; q < 16; ++q)
        lds[(h << 8) + (q << 4) + (cx ^ q)] = xi[PQ[q]];
    __syncthreads();
    #pragma unroll
    for (int q = 0; q < 16; ++q)
        xi[q] = lds[(jj << 8) + (h << 4) + (cx ^ q)];

    // ---- stage 2 fused with epilogue (nibble-swapped ownership) ----
    {
        pf yr[8], yi[8];
        dft16_mid8<1>(xr, xi, yr, yi);
        #pragma unroll
        for (int i2 = 0; i2 < 8; ++i2) {
            const pf m = yr[i2] * yr[i2] + yi[i2] * yi[i2];
            const float v0 = HALF_LN2 * __builtin_amdgcn_logf(m.x) - LOGN;
            const float v1 = HALF_LN2 * __builtin_amdgcn_logf(m.y) - LOGN;
            ((float2*)orow)[tid + 256 * i2] = make_float2(v0, v1);
        }
    }
}

// -------------------- one-shot ticket-fused kernel ---------------------------
// grid = B + B*NS blocks; each block draws ONE ticket and runs one body (no
// persistent loop -> regalloc sees a simple diamond, not R6/R8's loop-carried
// union that blew VGPR to 256).  The first 64 blocks TO START become fwd (so
// fwd always runs on resident blocks immediately); fwd never waits; any inv
// ticket implies its fwd ticket went earlier to a live block -> deadlock-free
// under any dispatch order.  Sync (fence + release flag / acquire spin with
// s_sleep) correctness-validated in R6.  Both bodies use the same 32 KB LDS.
__global__ __launch_bounds__(256) void fused_kernel(const float* __restrict__ in,
                                                    const float* __restrict__ wft,
                                                    float* __restrict__ out,
                                                    float2* __restrict__ F,
                                                    unsigned* __restrict__ ctrl,
                                                    int B, int NS) {
    __shared__ pf lds[NF];                   // 32 KB -> 5 blocks/CU
    __shared__ unsigned s_t;
    unsigned* flags = ctrl;                  // [0, B)
    unsigned* counter = ctrl + 256;          // separate cache line
    const int tid = threadIdx.x;

    if (tid == 0) s_t = atomicAdd(counter, 1u);
    __syncthreads();
    const unsigned t = s_t;

    if (t < (unsigned)B) {
        fwd_body(in, F, (float2*)lds, (int)t, tid);
        __threadfence();                     // publish F writes device-wide
        __syncthreads();
        if (tid == 0)
            __hip_atomic_store(&flags[t], 1u, __ATOMIC_RELEASE,
                               __HIP_MEMORY_SCOPE_AGENT);
    } else {
        const unsigned p = t - (unsigned)B;
        const int b = (int)(p / (unsigned)NS);
        const int j = (int)(p - (unsigned)b * (unsigned)NS);
        unsigned f;
        do {
            f = __hip_atomic_load(&flags[b], __ATOMIC_ACQUIRE,
                                  __HIP_MEMORY_SCOPE_AGENT);
            if (!f) __builtin_amdgcn_s_sleep(8);
        } while (!f);
        inv_body(F, wft, out, lds, b, j, tid, NS);
    }
}

extern "C" void kernel_launch(void* const* d_in, const int* in_sizes, int n_in,
                              void* d_out, int out_size, void* d_ws, size_t ws_size,
                              hipStream_t stream) {
    const float* inputs = (const float*)d_in[0];
    const float* wft = (const float*)d_in[1];
    float* out = (float*)d_out;

    const int B = in_sizes[0] / TT;     // 64
    const int NS = in_sizes[1] / NN;    // 75

    float2* F = (float2*)d_ws;                                   // B*4096 cplx = 2 MB
    unsigned* ctrl = (unsigned*)((char*)d_ws + (size_t)B * NF * sizeof(float2));

    hipMemsetAsync(ctrl, 0, 2048, stream);                       // flags + counter
    hipLaunchKernelGGL(fused_kernel, dim3(B + B * NS), dim3(256), 0, stream,
                       inputs, wft, out, F, ctrl, B, NS);
}